// Round 3
// baseline (310.549 us; speedup 1.0000x reference)
//
#include <hip/hip_runtime.h>
#include <stdint.h>

#define GRID_N (256*256*256)
#define MAXID 32
#define NCLS 13
#define NBINS ((MAXID+1)*NCLS)   // 429
#define PREP_BLOCKS 4096

// ws layout (bytes):
//   0     : int counts8[8][429]   (13728 B, zeroed via 16384-B memset)
//   16384 : uint seenArr[4096]    (16 KB, every entry written by its block -- no zeroing)
//   32768 : int glut[34+35]       (key->pano lut 0..33, then sem_lut[35])
//   49152 : uint8 key[GRID_N]     (16 MiB: bits 0..5 = inst id / 32=wall / 33=floor,
//                                  bit 6 = surface (|geo|<=1.5))

typedef int   iv4 __attribute__((ext_vector_type(4)));
typedef float fv4 __attribute__((ext_vector_type(4)));

__device__ __forceinline__ uint8_t keyb(int a, int b, float g) {
    int k = (b == 11) ? 33 : ((b == 10) ? 32 : a);
    return (uint8_t)(k | ((fabsf(g) <= 1.5f) ? 64 : 0));
}

// ---------------------------------------------------------------- pass 1
// Round-8: rounds 6/7 failed to force batch-issue (VGPR stayed 32) --
// 12 SEPARATE volatile asms only order each load before its OWN pin.
// This version pins all 12 loads (as 128-bit ext_vector "v" operands)
// in ONE volatile asm: every load must complete before the single
// sequence point -> all 12 simultaneously live -> batch-issue +
// clustered waitcnt is the only legal schedule. Readout: VGPR must
// jump to ~70-96; if dur stays ~86us anyway, latency-serialization
// theory is falsified (outstanding-miss cap) and we pivot.
__global__ __launch_bounds__(256) void k_prep(const float* __restrict__ geo,
                                              const int* __restrict__ inst,
                                              const int* __restrict__ sem,
                                              const int* __restrict__ ids2d, int n2d,
                                              int* __restrict__ counts8,
                                              unsigned int* __restrict__ seenArr,
                                              uint8_t* __restrict__ key) {
    __shared__ int sh[4][NBINS];
    __shared__ unsigned int wseen[4];
    int t = threadIdx.x;
    for (int i = t; i < 4 * NBINS; i += 256) ((int*)sh)[i] = 0;
    __syncthreads();
    int* myh = sh[t >> 6];

    // bit j of m <=> id j in (ids2d+1); eligC = classes not in {0,10,11}
    uint64_t m = 0;
    for (int k = 0; k < n2d; ++k) m |= 1ull << (ids2d[k] + 1);
    const unsigned int eligC = 0x13FE;

    unsigned int seen = 0;
    const int stride = PREP_BLOCKS * 256;
    const iv4* i4 = (const iv4*)inst;
    const iv4* s4 = (const iv4*)sem;
    const fv4* g4 = (const fv4*)geo;
    uchar4*    k4 = (uchar4*)key;

    const int idx0 = blockIdx.x * 256 + t;

    // ---- batch-issue all 12 loads; ONE asm pins all results live ----
    iv4 A[4]; iv4 B[4]; fv4 G[4];
    #pragma unroll
    for (int it = 0; it < 4; ++it) {
        int idx = idx0 + it * stride;
        A[it] = i4[idx];
        B[it] = s4[idx];
        G[it] = g4[idx];
    }
    asm volatile("" : "+v"(A[0]), "+v"(A[1]), "+v"(A[2]), "+v"(A[3]),
                      "+v"(B[0]), "+v"(B[1]), "+v"(B[2]), "+v"(B[3]),
                      "+v"(G[0]), "+v"(G[1]), "+v"(G[2]), "+v"(G[3]));

    #pragma unroll
    for (int it = 0; it < 4; ++it) {
        int idx = idx0 + it * stride;
        iv4 a = A[it];
        iv4 b = B[it];
        fv4 g = G[it];
        uchar4 kk;
        kk.x = keyb(a.x, b.x, g.x);
        kk.y = keyb(a.y, b.y, g.y);
        kk.z = keyb(a.z, b.z, g.z);
        kk.w = keyb(a.w, b.w, g.w);
        k4[idx] = kk;
        seen |= (1u << a.x) | (1u << a.y) | (1u << a.z) | (1u << a.w);
        if (((unsigned)(m >> a.x) & (eligC >> b.x)) & 1)
            atomicAdd(&myh[a.x * NCLS + b.x], 1);
        if (((unsigned)(m >> a.y) & (eligC >> b.y)) & 1)
            atomicAdd(&myh[a.y * NCLS + b.y], 1);
        if (((unsigned)(m >> a.z) & (eligC >> b.z)) & 1)
            atomicAdd(&myh[a.z * NCLS + b.z], 1);
        if (((unsigned)(m >> a.w) & (eligC >> b.w)) & 1)
            atomicAdd(&myh[a.w * NCLS + b.w], 1);
    }

    // block seen mask: wave shfl-reduce -> LDS -> one plain store (NO atomics)
    #pragma unroll
    for (int o = 32; o; o >>= 1) seen |= (unsigned int)__shfl_xor((int)seen, o);
    if ((t & 63) == 0) wseen[t >> 6] = seen;
    __syncthreads();
    if (t == 0)
        seenArr[blockIdx.x] = wseen[0] | wseen[1] | wseen[2] | wseen[3];

    int* dst = counts8 + (blockIdx.x & 7) * NBINS;
    for (int i = t; i < NBINS; i += 256) {
        int v = sh[0][i] + sh[1][i] + sh[2][i] + sh[3][i];
        if (v) atomicAdd(&dst[i], v);
    }
}

// ---------------------------------------------------------------- LUTs
__global__ __launch_bounds__(512) void k_luts(const int* __restrict__ counts8,
                                              const unsigned int* __restrict__ seenArr,
                                              const int* __restrict__ ids2d, int n2d,
                                              int* __restrict__ glut) {
    __shared__ int shc[NBINS];
    __shared__ int sem_s[35];
    __shared__ unsigned int wseen[8];
    int t = threadIdx.x;

    // parallel OR-reduce of 4096 per-block seen masks
    unsigned int s = 0;
    #pragma unroll
    for (int i = 0; i < 8; ++i) s |= seenArr[t + i * 512];
    #pragma unroll
    for (int o = 32; o; o >>= 1) s |= (unsigned int)__shfl_xor((int)s, o);
    if ((t & 63) == 0) wseen[t >> 6] = s;

    if (t < NBINS) {
        int acc = 0;
        #pragma unroll
        for (int c = 0; c < 8; ++c) acc += counts8[c * NBINS + t];
        shc[t] = acc;
    }
    __syncthreads();
    if (t < 64) {
        unsigned int seen = wseen[0] | wseen[1] | wseen[2] | wseen[3]
                          | wseen[4] | wseen[5] | wseen[6] | wseen[7];
        uint64_t m = 0;
        for (int k = 0; k < n2d; ++k) m |= 1ull << (ids2d[k] + 1);

        int in2d_t = (t <= MAXID) ? (int)((m >> t) & 1) : 0;
        int seen_t = (t < 32) ? (int)((seen >> t) & 1) : 0;
        int sel_t = 0;
        if (t <= MAXID) {
            int best = -2;
            for (int c = 0; c < NCLS; ++c) {
                int v = (c == 0 || c == 10 || c == 11) ? -1 : shc[t * NCLS + c];
                if (v > best) { best = v; sel_t = c; }
            }
        }
        // zero_present: any id 0..31 seen that is NOT in ids2d+1
        int zero_present = ((seen & ~(unsigned int)m) != 0u) ? 1 : 0;
        int pres = (t >= 1 && in2d_t && seen_t) ? 1 : 0;
        unsigned long long pm = __ballot(pres);
        int rank_below = __popcll(pm & ((1ULL << t) - 1ULL));
        int pano_id = pres ? (rank_below + zero_present + 2) : 0;

        if (t < 35) sem_s[t] = (t == 1) ? 10 : ((t == 2) ? 11 : 0);
        if (pres) sem_s[pano_id] = sel_t;   // disjoint ids; after defaults (same wave)

        if (t < 32) glut[t] = (t == 0) ? 0 : pano_id;   // key id -> pano id
        if (t == 32) glut[32] = 1;                      // wall
        if (t == 33) glut[33] = 2;                      // floor
        if (t < 35) glut[34 + t] = sem_s[t];            // sem_lut
    }
}

// ---------------------------------------------------------------- pass 2
// Tile = 8x8 (x,y) x full 256 z-line. LDS rows: 13x13 (x,y halo [-3,+2])
// x 264 bytes (z = -4..259 wrapped). Byte = grid0 | surface<<7.
#define TX 8
#define TY 8
#define HR 13              // TX+5
#define NROWS (HR*HR)      // 169
#define ROWDW 66           // 264 B per row
#define NDW (NROWS*ROWDW)  // 11154

__global__ __launch_bounds__(512) void k_nn(const uint8_t* __restrict__ key,
                                            const int* __restrict__ glut,
                                            int* __restrict__ out_pano,
                                            int* __restrict__ out_sem) {
    __shared__ uint32_t shg[NDW];     // 44616 B
    __shared__ int lut[128];          // key(7b incl surface) -> grid0 | surface<<7
    __shared__ int slut[MAXID + 3];

    int t = threadIdx.x;
    if (t < 128) {
        int base = ((t & 63) <= 33) ? glut[t & 63] : 0;
        lut[t] = base | ((t & 64) << 1);
    } else if (t >= 128 && t < 128 + MAXID + 3) {
        slut[t - 128] = glut[34 + (t - 128)];
    }
    __syncthreads();

    int x0 = blockIdx.x * TX;
    int y0 = blockIdx.y * TY;

    const uint32_t* key32 = (const uint32_t*)key;
    for (int idx = t; idx < NDW; idx += 512) {
        int row = idx / ROWDW;
        int k = idx - row * ROWDW;
        int ix = row / HR;
        int iy = row - ix * HR;
        int gx = (x0 + ix - 3) & 255;
        int gy = (y0 + iy - 3) & 255;
        uint32_t w = key32[(gx << 14) | (gy << 6) | ((k - 1) & 63)];
        shg[idx] = (uint32_t)lut[w & 127]
                 | ((uint32_t)lut[(w >> 8) & 127] << 8)
                 | ((uint32_t)lut[(w >> 16) & 127] << 16)
                 | ((uint32_t)lut[(w >> 24) & 127] << 24);
    }
    __syncthreads();

    int zg = t & 63;          // z-group: z = 4*zg .. 4*zg+3
    int ty = t >> 6;          // 0..7
    int gy = y0 + ty;
    const uint64_t M6 = 0x00007F7F7F7F7F7FULL;

    for (int x = 0; x < TX; ++x) {
        int gx = x0 + x;
        int r0 = (x + 3) * HR + (ty + 3);
        uint32_t cw = shg[r0 * ROWDW + zg + 1];   // 4 center bytes (z=4zg..+3)
        int4 pano, semv;
        int pv[4];
        #pragma unroll
        for (int b = 0; b < 4; ++b) {
            int v = (cw >> (8 * b)) & 255;
            int p = v & 127;
            if (p == 0 && (v & 128)) {
                int z = 4 * zg + b;
                int label = 0;
                int j0 = z + 1;
                int a0 = j0 >> 2, off = j0 & 3;
                for (int dxi = 0; dxi < 6 && !label; ++dxi) {
                    int rb = ((x + dxi) * HR + ty) * ROWDW + a0;
                    for (int dyi = 0; dyi < 6; ++dyi) {
                        int a = rb + dyi * ROWDW;
                        uint32_t d0 = shg[a], d1 = shg[a + 1], d2 = shg[a + 2];
                        uint64_t lo = (uint64_t)d0 | ((uint64_t)d1 << 32);
                        uint64_t win = lo >> (off * 8);
                        if (off) win |= (uint64_t)d2 << (64 - off * 8);
                        uint64_t mask = win & M6;   // 6 bytes, surface bit stripped
                        if (mask) {
                            int bb = __ffsll((long long)mask) - 1;
                            label = (int)((win >> (bb & 56)) & 0x7f);
                            break;
                        }
                    }
                }
                p = label;
            }
            pv[b] = p;
        }
        pano.x = pv[0]; pano.y = pv[1]; pano.z = pv[2]; pano.w = pv[3];
        semv.x = slut[pv[0]]; semv.y = slut[pv[1]]; semv.z = slut[pv[2]]; semv.w = slut[pv[3]];
        int oi = (gx << 14) | (gy << 6) | zg;     // int4 index
        ((int4*)out_pano)[oi] = pano;
        ((int4*)out_sem)[oi] = semv;
    }
}

extern "C" void kernel_launch(void* const* d_in, const int* in_sizes, int n_in,
                              void* d_out, int out_size, void* d_ws, size_t ws_size,
                              hipStream_t stream) {
    const float* geo   = (const float*)d_in[0];
    const int*   inst  = (const int*)d_in[1];
    const int*   sem   = (const int*)d_in[2];
    const int*   ids2d = (const int*)d_in[3];
    const int    n2d   = in_sizes[3];

    char* ws = (char*)d_ws;
    int* counts8           = (int*)(ws);
    unsigned int* seenArr  = (unsigned int*)(ws + 16384);
    int* glut              = (int*)(ws + 32768);
    uint8_t* key           = (uint8_t*)(ws + 49152);

    int* out_pano = (int*)d_out;
    int* out_sem  = out_pano + GRID_N;

    hipMemsetAsync(counts8, 0, 16384, stream);
    k_prep<<<PREP_BLOCKS, 256, 0, stream>>>(geo, inst, sem, ids2d, n2d,
                                            counts8, seenArr, key);
    k_luts<<<1, 512, 0, stream>>>(counts8, seenArr, ids2d, n2d, glut);
    dim3 g(32, 32);
    k_nn<<<g, 512, 0, stream>>>(key, glut, out_pano, out_sem);
}

// Round 4
// 307.193 us; speedup vs baseline: 1.0109x; 1.0109x over previous
//
#include <hip/hip_runtime.h>
#include <stdint.h>

#define GRID_N (256*256*256)
#define MAXID 32
#define NCLS 13
#define NBINS ((MAXID+1)*NCLS)   // 429
#define PREP_BLOCKS 2048         // round-9: 8 blocks/CU, ALL resident (32 waves/CU),
#define PREP_ITERS  8            // per-block tails (zero/barrier/flush/teardown) halved

// ws layout (bytes):
//   0     : int counts8[8][429]   (13728 B, zeroed via 16384-B memset)
//   16384 : uint seenArr[PREP_BLOCKS] (8 KB, every entry written by its block -- no zeroing)
//   32768 : int glut[34+35]       (key->pano lut 0..33, then sem_lut[35])
//   49152 : uint8 key[GRID_N]     (16 MiB: bits 0..5 = inst id / 32=wall / 33=floor,
//                                  bit 6 = surface (|geo|<=1.5))

__device__ __forceinline__ uint8_t keyb(int a, int b, float g) {
    int k = (b == 11) ? 33 : ((b == 10) ? 32 : a);
    return (uint8_t)(k | ((fabsf(g) <= 1.5f) ? 64 : 0));
}

// ---------------------------------------------------------------- pass 1
// Round-9 post-mortem of rounds 6-8: per-wave MLP went 1->3 loads in flight
// (VGPR 20->32) with ZERO bandwidth delta -> latency-serialization theory
// falsified. New theory: per-BLOCK structural overhead (LDS zero, 2 full
// vmcnt(0)-drain barriers, 429-bin global-atomic flush, ~3 block
// generations/CU) is the gap. Fix: 2048 blocks x 8 iters -- single fully
// resident generation, half the barriers/flush atomics. Body reverted to
// the clean round-5 schedule (pin asm scar tissue removed).
__global__ __launch_bounds__(256) void k_prep(const float* __restrict__ geo,
                                              const int* __restrict__ inst,
                                              const int* __restrict__ sem,
                                              const int* __restrict__ ids2d, int n2d,
                                              int* __restrict__ counts8,
                                              unsigned int* __restrict__ seenArr,
                                              uint8_t* __restrict__ key) {
    __shared__ int sh[4][NBINS];
    __shared__ unsigned int wseen[4];
    int t = threadIdx.x;
    for (int i = t; i < 4 * NBINS; i += 256) ((int*)sh)[i] = 0;
    __syncthreads();
    int* myh = sh[t >> 6];

    // bit j of m <=> id j in (ids2d+1); eligC = classes not in {0,10,11}
    uint64_t m = 0;
    for (int k = 0; k < n2d; ++k) m |= 1ull << (ids2d[k] + 1);
    const unsigned int eligC = 0x13FE;

    unsigned int seen = 0;
    const int stride = PREP_BLOCKS * 256;
    const int4*   i4 = (const int4*)inst;
    const int4*   s4 = (const int4*)sem;
    const float4* g4 = (const float4*)geo;
    uchar4*       k4 = (uchar4*)key;

    int idx = blockIdx.x * 256 + t;
    #pragma unroll 4
    for (int it = 0; it < PREP_ITERS; ++it, idx += stride) {
        int4 a = i4[idx];
        int4 b = s4[idx];
        float4 g = g4[idx];
        uchar4 kk;
        kk.x = keyb(a.x, b.x, g.x);
        kk.y = keyb(a.y, b.y, g.y);
        kk.z = keyb(a.z, b.z, g.z);
        kk.w = keyb(a.w, b.w, g.w);
        k4[idx] = kk;
        seen |= (1u << a.x) | (1u << a.y) | (1u << a.z) | (1u << a.w);
        if (((unsigned)(m >> a.x) & (eligC >> b.x)) & 1)
            atomicAdd(&myh[a.x * NCLS + b.x], 1);
        if (((unsigned)(m >> a.y) & (eligC >> b.y)) & 1)
            atomicAdd(&myh[a.y * NCLS + b.y], 1);
        if (((unsigned)(m >> a.z) & (eligC >> b.z)) & 1)
            atomicAdd(&myh[a.z * NCLS + b.z], 1);
        if (((unsigned)(m >> a.w) & (eligC >> b.w)) & 1)
            atomicAdd(&myh[a.w * NCLS + b.w], 1);
    }

    // block seen mask: wave shfl-reduce -> LDS -> one plain store (NO atomics)
    #pragma unroll
    for (int o = 32; o; o >>= 1) seen |= (unsigned int)__shfl_xor((int)seen, o);
    if ((t & 63) == 0) wseen[t >> 6] = seen;
    __syncthreads();
    if (t == 0)
        seenArr[blockIdx.x] = wseen[0] | wseen[1] | wseen[2] | wseen[3];

    int* dst = counts8 + (blockIdx.x & 7) * NBINS;
    for (int i = t; i < NBINS; i += 256) {
        int v = sh[0][i] + sh[1][i] + sh[2][i] + sh[3][i];
        if (v) atomicAdd(&dst[i], v);
    }
}

// ---------------------------------------------------------------- LUTs
__global__ __launch_bounds__(512) void k_luts(const int* __restrict__ counts8,
                                              const unsigned int* __restrict__ seenArr,
                                              const int* __restrict__ ids2d, int n2d,
                                              int* __restrict__ glut) {
    __shared__ int shc[NBINS];
    __shared__ int sem_s[35];
    __shared__ unsigned int wseen[8];
    int t = threadIdx.x;

    // parallel OR-reduce of PREP_BLOCKS per-block seen masks
    unsigned int s = 0;
    #pragma unroll
    for (int i = 0; i < PREP_BLOCKS / 512; ++i) s |= seenArr[t + i * 512];
    #pragma unroll
    for (int o = 32; o; o >>= 1) s |= (unsigned int)__shfl_xor((int)s, o);
    if ((t & 63) == 0) wseen[t >> 6] = s;

    if (t < NBINS) {
        int acc = 0;
        #pragma unroll
        for (int c = 0; c < 8; ++c) acc += counts8[c * NBINS + t];
        shc[t] = acc;
    }
    __syncthreads();
    if (t < 64) {
        unsigned int seen = wseen[0] | wseen[1] | wseen[2] | wseen[3]
                          | wseen[4] | wseen[5] | wseen[6] | wseen[7];
        uint64_t m = 0;
        for (int k = 0; k < n2d; ++k) m |= 1ull << (ids2d[k] + 1);

        int in2d_t = (t <= MAXID) ? (int)((m >> t) & 1) : 0;
        int seen_t = (t < 32) ? (int)((seen >> t) & 1) : 0;
        int sel_t = 0;
        if (t <= MAXID) {
            int best = -2;
            for (int c = 0; c < NCLS; ++c) {
                int v = (c == 0 || c == 10 || c == 11) ? -1 : shc[t * NCLS + c];
                if (v > best) { best = v; sel_t = c; }
            }
        }
        // zero_present: any id 0..31 seen that is NOT in ids2d+1
        int zero_present = ((seen & ~(unsigned int)m) != 0u) ? 1 : 0;
        int pres = (t >= 1 && in2d_t && seen_t) ? 1 : 0;
        unsigned long long pm = __ballot(pres);
        int rank_below = __popcll(pm & ((1ULL << t) - 1ULL));
        int pano_id = pres ? (rank_below + zero_present + 2) : 0;

        if (t < 35) sem_s[t] = (t == 1) ? 10 : ((t == 2) ? 11 : 0);
        if (pres) sem_s[pano_id] = sel_t;   // disjoint ids; after defaults (same wave)

        if (t < 32) glut[t] = (t == 0) ? 0 : pano_id;   // key id -> pano id
        if (t == 32) glut[32] = 1;                      // wall
        if (t == 33) glut[33] = 2;                      // floor
        if (t < 35) glut[34 + t] = sem_s[t];            // sem_lut
    }
}

// ---------------------------------------------------------------- pass 2
// Tile = 8x8 (x,y) x full 256 z-line. LDS rows: 13x13 (x,y halo [-3,+2])
// x 264 bytes (z = -4..259 wrapped). Byte = grid0 | surface<<7.
#define TX 8
#define TY 8
#define HR 13              // TX+5
#define NROWS (HR*HR)      // 169
#define ROWDW 66           // 264 B per row
#define NDW (NROWS*ROWDW)  // 11154

__global__ __launch_bounds__(512) void k_nn(const uint8_t* __restrict__ key,
                                            const int* __restrict__ glut,
                                            int* __restrict__ out_pano,
                                            int* __restrict__ out_sem) {
    __shared__ uint32_t shg[NDW];     // 44616 B
    __shared__ int lut[128];          // key(7b incl surface) -> grid0 | surface<<7
    __shared__ int slut[MAXID + 3];

    int t = threadIdx.x;
    if (t < 128) {
        int base = ((t & 63) <= 33) ? glut[t & 63] : 0;
        lut[t] = base | ((t & 64) << 1);
    } else if (t >= 128 && t < 128 + MAXID + 3) {
        slut[t - 128] = glut[34 + (t - 128)];
    }
    __syncthreads();

    int x0 = blockIdx.x * TX;
    int y0 = blockIdx.y * TY;

    const uint32_t* key32 = (const uint32_t*)key;
    for (int idx = t; idx < NDW; idx += 512) {
        int row = idx / ROWDW;
        int k = idx - row * ROWDW;
        int ix = row / HR;
        int iy = row - ix * HR;
        int gx = (x0 + ix - 3) & 255;
        int gy = (y0 + iy - 3) & 255;
        uint32_t w = key32[(gx << 14) | (gy << 6) | ((k - 1) & 63)];
        shg[idx] = (uint32_t)lut[w & 127]
                 | ((uint32_t)lut[(w >> 8) & 127] << 8)
                 | ((uint32_t)lut[(w >> 16) & 127] << 16)
                 | ((uint32_t)lut[(w >> 24) & 127] << 24);
    }
    __syncthreads();

    int zg = t & 63;          // z-group: z = 4*zg .. 4*zg+3
    int ty = t >> 6;          // 0..7
    int gy = y0 + ty;
    const uint64_t M6 = 0x00007F7F7F7F7F7FULL;

    for (int x = 0; x < TX; ++x) {
        int gx = x0 + x;
        int r0 = (x + 3) * HR + (ty + 3);
        uint32_t cw = shg[r0 * ROWDW + zg + 1];   // 4 center bytes (z=4zg..+3)
        int4 pano, semv;
        int pv[4];
        #pragma unroll
        for (int b = 0; b < 4; ++b) {
            int v = (cw >> (8 * b)) & 255;
            int p = v & 127;
            if (p == 0 && (v & 128)) {
                int z = 4 * zg + b;
                int label = 0;
                int j0 = z + 1;
                int a0 = j0 >> 2, off = j0 & 3;
                for (int dxi = 0; dxi < 6 && !label; ++dxi) {
                    int rb = ((x + dxi) * HR + ty) * ROWDW + a0;
                    for (int dyi = 0; dyi < 6; ++dyi) {
                        int a = rb + dyi * ROWDW;
                        uint32_t d0 = shg[a], d1 = shg[a + 1], d2 = shg[a + 2];
                        uint64_t lo = (uint64_t)d0 | ((uint64_t)d1 << 32);
                        uint64_t win = lo >> (off * 8);
                        if (off) win |= (uint64_t)d2 << (64 - off * 8);
                        uint64_t mask = win & M6;   // 6 bytes, surface bit stripped
                        if (mask) {
                            int bb = __ffsll((long long)mask) - 1;
                            label = (int)((win >> (bb & 56)) & 0x7f);
                            break;
                        }
                    }
                }
                p = label;
            }
            pv[b] = p;
        }
        pano.x = pv[0]; pano.y = pv[1]; pano.z = pv[2]; pano.w = pv[3];
        semv.x = slut[pv[0]]; semv.y = slut[pv[1]]; semv.z = slut[pv[2]]; semv.w = slut[pv[3]];
        int oi = (gx << 14) | (gy << 6) | zg;     // int4 index
        ((int4*)out_pano)[oi] = pano;
        ((int4*)out_sem)[oi] = semv;
    }
}

extern "C" void kernel_launch(void* const* d_in, const int* in_sizes, int n_in,
                              void* d_out, int out_size, void* d_ws, size_t ws_size,
                              hipStream_t stream) {
    const float* geo   = (const float*)d_in[0];
    const int*   inst  = (const int*)d_in[1];
    const int*   sem   = (const int*)d_in[2];
    const int*   ids2d = (const int*)d_in[3];
    const int    n2d   = in_sizes[3];

    char* ws = (char*)d_ws;
    int* counts8           = (int*)(ws);
    unsigned int* seenArr  = (unsigned int*)(ws + 16384);
    int* glut              = (int*)(ws + 32768);
    uint8_t* key           = (uint8_t*)(ws + 49152);

    int* out_pano = (int*)d_out;
    int* out_sem  = out_pano + GRID_N;

    hipMemsetAsync(counts8, 0, 16384, stream);
    k_prep<<<PREP_BLOCKS, 256, 0, stream>>>(geo, inst, sem, ids2d, n2d,
                                            counts8, seenArr, key);
    k_luts<<<1, 512, 0, stream>>>(counts8, seenArr, ids2d, n2d, glut);
    dim3 g(32, 32);
    k_nn<<<g, 512, 0, stream>>>(key, glut, out_pano, out_sem);
}

// Round 5
// 306.574 us; speedup vs baseline: 1.0130x; 1.0020x over previous
//
#include <hip/hip_runtime.h>
#include <stdint.h>

#define GRID_N (256*256*256)
#define MAXID 32
#define NCLS 13
#define NBINS ((MAXID+1)*NCLS)   // 429
#define PREP_BLOCKS 2048         // 8 blocks/CU, all resident (round-9 win: -6us)
#define PREP_ITERS  8

// ws layout (bytes):
//   0     : int counts8[8][429]   (13728 B, zeroed via 16384-B memset)
//   16384 : uint seenArr[PREP_BLOCKS] (8 KB, every entry written by its block -- no zeroing)
//   32768 : int glut[34+35]       (key->pano lut 0..33, then sem_lut[35])
//   49152 : uint8 key[GRID_N]     (16 MiB: bits 0..5 = inst id / 32=wall / 33=floor,
//                                  bit 6 = surface (|geo|<=1.5))

typedef int   iv4 __attribute__((ext_vector_type(4)));
typedef float fv4 __attribute__((ext_vector_type(4)));

__device__ __forceinline__ uint8_t keyb(int a, int b, float g) {
    int k = (b == 11) ? 33 : ((b == 10) ? 32 : a);
    return (uint8_t)(k | ((fabsf(g) <= 1.5f) ? 64 : 0));
}

// ---------------------------------------------------------------- pass 1
// Round-10: rounds 6-8 post-mortem correction -- R0's VGPR=20 already held 3
// clustered loads, so MLP was 3 all along and the latency theory was never
// tested above that. This version is a TRUE depth-2 pipeline the compiler
// cannot collapse: volatile asm global_load_dwordx4 (unsinkable, mutually
// ordered) + hand-counted s_waitcnt vmcnt(3) whose "+v"-pinned operands
// dataflow-order the consume. Steady state: loads(K+1) in flight while
// computing K. vmcnt: {loads(K),store(K-1),loads(K+1)} outstanding -> 3.
__global__ __launch_bounds__(256) void k_prep(const float* __restrict__ geo,
                                              const int* __restrict__ inst,
                                              const int* __restrict__ sem,
                                              const int* __restrict__ ids2d, int n2d,
                                              int* __restrict__ counts8,
                                              unsigned int* __restrict__ seenArr,
                                              uint8_t* __restrict__ key) {
    __shared__ int sh[4][NBINS];
    __shared__ unsigned int wseen[4];
    int t = threadIdx.x;
    for (int i = t; i < 4 * NBINS; i += 256) ((int*)sh)[i] = 0;
    __syncthreads();
    int* myh = sh[t >> 6];

    // bit j of m <=> id j in (ids2d+1); eligC = classes not in {0,10,11}
    uint64_t m = 0;
    for (int k = 0; k < n2d; ++k) m |= 1ull << (ids2d[k] + 1);
    const unsigned int eligC = 0x13FE;

    unsigned int seen = 0;
    const int stride = PREP_BLOCKS * 256;
    const iv4* i4 = (const iv4*)inst;
    const iv4* s4 = (const iv4*)sem;
    const fv4* g4 = (const fv4*)geo;
    uchar4*    k4 = (uchar4*)key;

    const int idx0 = blockIdx.x * 256 + t;

    iv4 A0, B0, A1, B1; fv4 G0, G1;

    // issue 3 loads for tile (ofs) -- opaque to the compiler, cannot be sunk
#define LD3(A, B, G, ofs) do {                                            \
        uint64_t _pa = (uint64_t)(i4 + (ofs));                            \
        uint64_t _pb = (uint64_t)(s4 + (ofs));                            \
        uint64_t _pg = (uint64_t)(g4 + (ofs));                            \
        asm volatile("global_load_dwordx4 %0, %1, off"                    \
                     : "=&v"(A) : "v"(_pa) : "memory");                   \
        asm volatile("global_load_dwordx4 %0, %1, off"                    \
                     : "=&v"(B) : "v"(_pb) : "memory");                   \
        asm volatile("global_load_dwordx4 %0, %1, off"                    \
                     : "=&v"(G) : "v"(_pg) : "memory");                   \
    } while (0)

    // counted wait; "+v" pins dataflow so consumers cannot hoist above it
#define WAITPIN(A, B, G, N)                                               \
    asm volatile("s_waitcnt vmcnt(" #N ")" : "+v"(A), "+v"(B), "+v"(G))

#define PROC(A, B, G, ofs) do {                                           \
        iv4 a = (A); iv4 b = (B); fv4 g = (G);                            \
        int _idx = (ofs);                                                 \
        uchar4 kk;                                                        \
        kk.x = keyb(a.x, b.x, g.x);                                       \
        kk.y = keyb(a.y, b.y, g.y);                                       \
        kk.z = keyb(a.z, b.z, g.z);                                       \
        kk.w = keyb(a.w, b.w, g.w);                                       \
        k4[_idx] = kk;                                                    \
        seen |= (1u << a.x) | (1u << a.y) | (1u << a.z) | (1u << a.w);    \
        if (((unsigned)(m >> a.x) & (eligC >> b.x)) & 1)                  \
            atomicAdd(&myh[a.x * NCLS + b.x], 1);                         \
        if (((unsigned)(m >> a.y) & (eligC >> b.y)) & 1)                  \
            atomicAdd(&myh[a.y * NCLS + b.y], 1);                         \
        if (((unsigned)(m >> a.z) & (eligC >> b.z)) & 1)                  \
            atomicAdd(&myh[a.z * NCLS + b.z], 1);                         \
        if (((unsigned)(m >> a.w) & (eligC >> b.w)) & 1)                  \
            atomicAdd(&myh[a.w * NCLS + b.w], 1);                         \
    } while (0)

    // depth-2 ping-pong over 8 tiles
    LD3(A0, B0, G0, idx0 + 0 * stride);
    LD3(A1, B1, G1, idx0 + 1 * stride);
    WAITPIN(A0, B0, G0, 3); PROC(A0, B0, G0, idx0 + 0 * stride);
    LD3(A0, B0, G0, idx0 + 2 * stride);
    WAITPIN(A1, B1, G1, 3); PROC(A1, B1, G1, idx0 + 1 * stride);
    LD3(A1, B1, G1, idx0 + 3 * stride);
    WAITPIN(A0, B0, G0, 3); PROC(A0, B0, G0, idx0 + 2 * stride);
    LD3(A0, B0, G0, idx0 + 4 * stride);
    WAITPIN(A1, B1, G1, 3); PROC(A1, B1, G1, idx0 + 3 * stride);
    LD3(A1, B1, G1, idx0 + 5 * stride);
    WAITPIN(A0, B0, G0, 3); PROC(A0, B0, G0, idx0 + 4 * stride);
    LD3(A0, B0, G0, idx0 + 6 * stride);
    WAITPIN(A1, B1, G1, 3); PROC(A1, B1, G1, idx0 + 5 * stride);
    LD3(A1, B1, G1, idx0 + 7 * stride);
    WAITPIN(A0, B0, G0, 3); PROC(A0, B0, G0, idx0 + 6 * stride);
    WAITPIN(A1, B1, G1, 0); PROC(A1, B1, G1, idx0 + 7 * stride);

#undef LD3
#undef WAITPIN
#undef PROC

    // block seen mask: wave shfl-reduce -> LDS -> one plain store (NO atomics)
    #pragma unroll
    for (int o = 32; o; o >>= 1) seen |= (unsigned int)__shfl_xor((int)seen, o);
    if ((t & 63) == 0) wseen[t >> 6] = seen;
    __syncthreads();
    if (t == 0)
        seenArr[blockIdx.x] = wseen[0] | wseen[1] | wseen[2] | wseen[3];

    int* dst = counts8 + (blockIdx.x & 7) * NBINS;
    for (int i = t; i < NBINS; i += 256) {
        int v = sh[0][i] + sh[1][i] + sh[2][i] + sh[3][i];
        if (v) atomicAdd(&dst[i], v);
    }
}

// ---------------------------------------------------------------- LUTs
__global__ __launch_bounds__(512) void k_luts(const int* __restrict__ counts8,
                                              const unsigned int* __restrict__ seenArr,
                                              const int* __restrict__ ids2d, int n2d,
                                              int* __restrict__ glut) {
    __shared__ int shc[NBINS];
    __shared__ int sem_s[35];
    __shared__ unsigned int wseen[8];
    int t = threadIdx.x;

    // parallel OR-reduce of PREP_BLOCKS per-block seen masks
    unsigned int s = 0;
    #pragma unroll
    for (int i = 0; i < PREP_BLOCKS / 512; ++i) s |= seenArr[t + i * 512];
    #pragma unroll
    for (int o = 32; o; o >>= 1) s |= (unsigned int)__shfl_xor((int)s, o);
    if ((t & 63) == 0) wseen[t >> 6] = s;

    if (t < NBINS) {
        int acc = 0;
        #pragma unroll
        for (int c = 0; c < 8; ++c) acc += counts8[c * NBINS + t];
        shc[t] = acc;
    }
    __syncthreads();
    if (t < 64) {
        unsigned int seen = wseen[0] | wseen[1] | wseen[2] | wseen[3]
                          | wseen[4] | wseen[5] | wseen[6] | wseen[7];
        uint64_t m = 0;
        for (int k = 0; k < n2d; ++k) m |= 1ull << (ids2d[k] + 1);

        int in2d_t = (t <= MAXID) ? (int)((m >> t) & 1) : 0;
        int seen_t = (t < 32) ? (int)((seen >> t) & 1) : 0;
        int sel_t = 0;
        if (t <= MAXID) {
            int best = -2;
            for (int c = 0; c < NCLS; ++c) {
                int v = (c == 0 || c == 10 || c == 11) ? -1 : shc[t * NCLS + c];
                if (v > best) { best = v; sel_t = c; }
            }
        }
        // zero_present: any id 0..31 seen that is NOT in ids2d+1
        int zero_present = ((seen & ~(unsigned int)m) != 0u) ? 1 : 0;
        int pres = (t >= 1 && in2d_t && seen_t) ? 1 : 0;
        unsigned long long pm = __ballot(pres);
        int rank_below = __popcll(pm & ((1ULL << t) - 1ULL));
        int pano_id = pres ? (rank_below + zero_present + 2) : 0;

        if (t < 35) sem_s[t] = (t == 1) ? 10 : ((t == 2) ? 11 : 0);
        if (pres) sem_s[pano_id] = sel_t;   // disjoint ids; after defaults (same wave)

        if (t < 32) glut[t] = (t == 0) ? 0 : pano_id;   // key id -> pano id
        if (t == 32) glut[32] = 1;                      // wall
        if (t == 33) glut[33] = 2;                      // floor
        if (t < 35) glut[34 + t] = sem_s[t];            // sem_lut
    }
}

// ---------------------------------------------------------------- pass 2
// Tile = 8x8 (x,y) x full 256 z-line. LDS rows: 13x13 (x,y halo [-3,+2])
// x 264 bytes (z = -4..259 wrapped). Byte = grid0 | surface<<7.
#define TX 8
#define TY 8
#define HR 13              // TX+5
#define NROWS (HR*HR)      // 169
#define ROWDW 66           // 264 B per row
#define NDW (NROWS*ROWDW)  // 11154

__global__ __launch_bounds__(512) void k_nn(const uint8_t* __restrict__ key,
                                            const int* __restrict__ glut,
                                            int* __restrict__ out_pano,
                                            int* __restrict__ out_sem) {
    __shared__ uint32_t shg[NDW];     // 44616 B
    __shared__ int lut[128];          // key(7b incl surface) -> grid0 | surface<<7
    __shared__ int slut[MAXID + 3];

    int t = threadIdx.x;
    if (t < 128) {
        int base = ((t & 63) <= 33) ? glut[t & 63] : 0;
        lut[t] = base | ((t & 64) << 1);
    } else if (t >= 128 && t < 128 + MAXID + 3) {
        slut[t - 128] = glut[34 + (t - 128)];
    }
    __syncthreads();

    int x0 = blockIdx.x * TX;
    int y0 = blockIdx.y * TY;

    const uint32_t* key32 = (const uint32_t*)key;
    for (int idx = t; idx < NDW; idx += 512) {
        int row = idx / ROWDW;
        int k = idx - row * ROWDW;
        int ix = row / HR;
        int iy = row - ix * HR;
        int gx = (x0 + ix - 3) & 255;
        int gy = (y0 + iy - 3) & 255;
        uint32_t w = key32[(gx << 14) | (gy << 6) | ((k - 1) & 63)];
        shg[idx] = (uint32_t)lut[w & 127]
                 | ((uint32_t)lut[(w >> 8) & 127] << 8)
                 | ((uint32_t)lut[(w >> 16) & 127] << 16)
                 | ((uint32_t)lut[(w >> 24) & 127] << 24);
    }
    __syncthreads();

    int zg = t & 63;          // z-group: z = 4*zg .. 4*zg+3
    int ty = t >> 6;          // 0..7
    int gy = y0 + ty;
    const uint64_t M6 = 0x00007F7F7F7F7F7FULL;

    for (int x = 0; x < TX; ++x) {
        int gx = x0 + x;
        int r0 = (x + 3) * HR + (ty + 3);
        uint32_t cw = shg[r0 * ROWDW + zg + 1];   // 4 center bytes (z=4zg..+3)
        int4 pano, semv;
        int pv[4];
        #pragma unroll
        for (int b = 0; b < 4; ++b) {
            int v = (cw >> (8 * b)) & 255;
            int p = v & 127;
            if (p == 0 && (v & 128)) {
                int z = 4 * zg + b;
                int label = 0;
                int j0 = z + 1;
                int a0 = j0 >> 2, off = j0 & 3;
                for (int dxi = 0; dxi < 6 && !label; ++dxi) {
                    int rb = ((x + dxi) * HR + ty) * ROWDW + a0;
                    for (int dyi = 0; dyi < 6; ++dyi) {
                        int a = rb + dyi * ROWDW;
                        uint32_t d0 = shg[a], d1 = shg[a + 1], d2 = shg[a + 2];
                        uint64_t lo = (uint64_t)d0 | ((uint64_t)d1 << 32);
                        uint64_t win = lo >> (off * 8);
                        if (off) win |= (uint64_t)d2 << (64 - off * 8);
                        uint64_t mask = win & M6;   // 6 bytes, surface bit stripped
                        if (mask) {
                            int bb = __ffsll((long long)mask) - 1;
                            label = (int)((win >> (bb & 56)) & 0x7f);
                            break;
                        }
                    }
                }
                p = label;
            }
            pv[b] = p;
        }
        pano.x = pv[0]; pano.y = pv[1]; pano.z = pv[2]; pano.w = pv[3];
        semv.x = slut[pv[0]]; semv.y = slut[pv[1]]; semv.z = slut[pv[2]]; semv.w = slut[pv[3]];
        int oi = (gx << 14) | (gy << 6) | zg;     // int4 index
        ((int4*)out_pano)[oi] = pano;
        ((int4*)out_sem)[oi] = semv;
    }
}

extern "C" void kernel_launch(void* const* d_in, const int* in_sizes, int n_in,
                              void* d_out, int out_size, void* d_ws, size_t ws_size,
                              hipStream_t stream) {
    const float* geo   = (const float*)d_in[0];
    const int*   inst  = (const int*)d_in[1];
    const int*   sem   = (const int*)d_in[2];
    const int*   ids2d = (const int*)d_in[3];
    const int    n2d   = in_sizes[3];

    char* ws = (char*)d_ws;
    int* counts8           = (int*)(ws);
    unsigned int* seenArr  = (unsigned int*)(ws + 16384);
    int* glut              = (int*)(ws + 32768);
    uint8_t* key           = (uint8_t*)(ws + 49152);

    int* out_pano = (int*)d_out;
    int* out_sem  = out_pano + GRID_N;

    hipMemsetAsync(counts8, 0, 16384, stream);
    k_prep<<<PREP_BLOCKS, 256, 0, stream>>>(geo, inst, sem, ids2d, n2d,
                                            counts8, seenArr, key);
    k_luts<<<1, 512, 0, stream>>>(counts8, seenArr, ids2d, n2d, glut);
    dim3 g(32, 32);
    k_nn<<<g, 512, 0, stream>>>(key, glut, out_pano, out_sem);
}